// Round 1
// baseline (1158.001 us; speedup 1.0000x reference)
//
#include <hip/hip_runtime.h>
#include <cmath>

namespace {

constexpr int XC = 64, XH = 128, XW = 128;
constexpr int NSEQ = 128;   // B(2) * 64 cubes
constexpr int TLEN = 1025;  // gt token + 1024
constexpr int LSEQ = 1024;

__device__ __forceinline__ int xidx(int b, int c, int h, int w) {
    return ((b * XC + c) * XH + h) * XW + w;
}
// reference's final reassembly: out4.reshape(B,nc,Co,Ho,Wo).transpose(0,2,1,3,4)
//   .reshape(B,Co,128,128): linear=(cube*256+i*16+j) -> h=lin>>7, w=lin&127
__device__ __forceinline__ int oidx(int b, int cube, int c, int i, int j) {
    int h = cube * 2 + (i >> 3);
    int w = ((i & 7) << 4) | j;
    return xidx(b, c, h, w);
}
__device__ __forceinline__ float siluf(float v) { return v / (1.0f + __expf(-v)); }
__device__ __forceinline__ float softplusf(float v) {
    return v > 20.0f ? v : log1pf(__expf(v));
}

// ---------------- phase 1a: gather + layernorm + in-proj (16 -> 64) ----------
template <int MODE>
__global__ void k_p1a(const float* __restrict__ x, const float* __restrict__ gt,
                      const float* __restrict__ lng, const float* __restrict__ lnb,
                      const float* __restrict__ in_w,  // (64,16)
                      float* __restrict__ xz)          // (NSEQ,TLEN,64): [0:32]=xi [32:64]=z
{
    __shared__ float s_w[64 * 16];
    __shared__ float s_g[16], s_b[16], s_gt[16];
    for (int i = threadIdx.x; i < 64 * 16; i += blockDim.x) s_w[i] = in_w[i];
    if (threadIdx.x < 16) {
        s_g[threadIdx.x] = lng[threadIdx.x];
        s_b[threadIdx.x] = lnb[threadIdx.x];
        s_gt[threadIdx.x] = gt[threadIdx.x];
    }
    __syncthreads();
    int tid = blockIdx.x * blockDim.x + threadIdx.x;
    if (tid >= NSEQ * TLEN) return;
    int n = tid / TLEN, t = tid - n * TLEN;

    float v[16];
    if (t == 0) {
#pragma unroll
        for (int i = 0; i < 16; i++) v[i] = s_gt[i];
    } else {
        int l = t - 1;
        int b = n >> 6, cube = n & 63, bi = cube >> 3, bj = cube & 7;
        if (MODE == 0) {
            // token l=(i2,j2) of pixelshuffled cube; v[d]=x[b, d*4+coff, bi*16+(i2>>1), bj*16+(j2>>1)]
            int i2 = l >> 5, j2 = l & 31;
            int h = bi * 16 + (i2 >> 1), w = bj * 16 + (j2 >> 1);
            int coff = ((i2 & 1) << 1) | (j2 & 1);
#pragma unroll
            for (int i = 0; i < 16; i++) v[i] = x[xidx(b, i * 4 + coff, h, w)];
        } else if (MODE == 1) {
            int c = l >> 4, j = l & 15;
            int w = bj * 16 + j;
#pragma unroll
            for (int i = 0; i < 16; i++) v[i] = x[xidx(b, c, bi * 16 + i, w)];
        } else {
            int c = l >> 4, i = l & 15;
            int h = bi * 16 + i;
#pragma unroll
            for (int j = 0; j < 16; j++) v[j] = x[xidx(b, c, h, bj * 16 + j)];
        }
    }
    // layernorm over 16
    float mu = 0.f;
#pragma unroll
    for (int i = 0; i < 16; i++) mu += v[i];
    mu *= (1.0f / 16.0f);
    float var = 0.f;
#pragma unroll
    for (int i = 0; i < 16; i++) { float d = v[i] - mu; var += d * d; }
    var *= (1.0f / 16.0f);
    float inv = rsqrtf(var + 1e-5f);
#pragma unroll
    for (int i = 0; i < 16; i++) v[i] = (v[i] - mu) * inv * s_g[i] + s_b[i];
    // in-proj
    float* o = xz + (size_t)tid * 64;
#pragma unroll
    for (int oc = 0; oc < 64; oc++) {
        float acc = 0.f;
#pragma unroll
        for (int i = 0; i < 16; i++) acc += v[i] * s_w[oc * 16 + i];
        o[oc] = acc;
    }
}

// ------------- phase 1b: causal conv4 + silu + x-proj + dt/softplus ----------
__global__ void k_p1b(const float* __restrict__ xz,
                      const float* __restrict__ conv_w,  // (32,4)
                      const float* __restrict__ conv_b,  // (32)
                      const float* __restrict__ xproj_w, // (33,32)
                      const float* __restrict__ dt_w,    // (32,1)
                      const float* __restrict__ dt_b,    // (32)
                      float* __restrict__ sc)            // (NSEQ,TLEN,96): xc[32] dt[32] B[16] C[16]
{
    __shared__ float s_xp[33 * 32];
    __shared__ float s_cw[32 * 4], s_cb[32], s_dw[32], s_db[32];
    for (int i = threadIdx.x; i < 33 * 32; i += blockDim.x) s_xp[i] = xproj_w[i];
    for (int i = threadIdx.x; i < 128; i += blockDim.x) s_cw[i] = conv_w[i];
    if (threadIdx.x < 32) {
        s_cb[threadIdx.x] = conv_b[threadIdx.x];
        s_dw[threadIdx.x] = dt_w[threadIdx.x];
        s_db[threadIdx.x] = dt_b[threadIdx.x];
    }
    __syncthreads();
    int tid = blockIdx.x * blockDim.x + threadIdx.x;
    if (tid >= NSEQ * TLEN) return;
    int n = tid / TLEN, t = tid - n * TLEN;
    const float* xzn = xz + (size_t)n * TLEN * 64;

    float xc[32];
#pragma unroll
    for (int c = 0; c < 32; c++) xc[c] = 0.f;
#pragma unroll
    for (int k = 0; k < 4; k++) {
        int tk = t - 3 + k;
        if (tk >= 0) {
            const float* row = xzn + (size_t)tk * 64;
#pragma unroll
            for (int c = 0; c < 32; c++) xc[c] += s_cw[c * 4 + k] * row[c];
        }
    }
#pragma unroll
    for (int c = 0; c < 32; c++) xc[c] = siluf(xc[c] + s_cb[c]);

    float dt0 = 0.f;
#pragma unroll
    for (int c = 0; c < 32; c++) dt0 += xc[c] * s_xp[c];  // x_dbl row 0 (dt_rank=1)

    float* out = sc + (size_t)tid * 96;
#pragma unroll
    for (int c = 0; c < 32; c++) out[c] = xc[c];
#pragma unroll
    for (int d = 0; d < 32; d++) out[32 + d] = softplusf(dt0 * s_dw[d] + s_db[d]);
#pragma unroll
    for (int r = 0; r < 32; r++) {  // rows 1..32 -> B[0:16], C[0:16]
        float acc = 0.f;
#pragma unroll
        for (int c = 0; c < 32; c++) acc += xc[c] * s_xp[(1 + r) * 32 + c];
        out[64 + r] = acc;
    }
}

// ---------------- phase 2: sequential selective scan ------------------------
__global__ __launch_bounds__(512) void k_scan(const float* __restrict__ sc,
                                              const float* __restrict__ A_log, // (32,16)
                                              const float* __restrict__ Dp,    // (32)
                                              float* __restrict__ yc)          // (NSEQ,TLEN,32)
{
    int n = blockIdx.x;
    int tid = threadIdx.x;
    int d = tid >> 4, s = tid & 15;
    float A = -__expf(A_log[d * 16 + s]);
    float Dd = Dp[d];
    const float* base = sc + (size_t)n * TLEN * 96;
    float* yb = yc + (size_t)n * TLEN * 32;

    float h = 0.f;
    float dt_c = base[32 + d], xc_c = base[d], Bv_c = base[64 + s], Cv_c = base[80 + s];
    for (int t = 0; t < TLEN; t++) {
        int tn = t + 1 < TLEN ? t + 1 : t;  // prefetch next token (clamped)
        const float* p = base + (size_t)tn * 96;
        float dt_n = p[32 + d];
        float xc_n = p[d];
        float Bv_n = p[64 + s];
        float Cv_n = p[80 + s];

        float a = __expf(dt_c * A);
        h = a * h + dt_c * Bv_c * xc_c;
        float pp = h * Cv_c;
        pp += __shfl_xor(pp, 1);
        pp += __shfl_xor(pp, 2);
        pp += __shfl_xor(pp, 4);
        pp += __shfl_xor(pp, 8);
        if (s == 0) yb[(size_t)t * 32 + d] = pp + Dd * xc_c;

        dt_c = dt_n; xc_c = xc_n; Bv_c = Bv_n; Cv_c = Cv_n;
    }
}

// ---------------- phase 3: gate + out-proj + scatter ------------------------
template <int MODE>
__global__ void k_p3(const float* __restrict__ yc, const float* __restrict__ xz,
                     const float* __restrict__ out_w,  // (16,32)
                     float* __restrict__ out)
{
    __shared__ float s_w[16 * 32];
    for (int i = threadIdx.x; i < 512; i += blockDim.x) s_w[i] = out_w[i];
    __syncthreads();
    int tid = blockIdx.x * blockDim.x + threadIdx.x;
    if (tid >= NSEQ * LSEQ) return;
    int n = tid >> 10, l = tid & 1023, t = l + 1;
    const float* y = yc + ((size_t)n * TLEN + t) * 32;
    const float* z = xz + ((size_t)n * TLEN + t) * 64 + 32;
    float yv[32];
#pragma unroll
    for (int c = 0; c < 32; c++) yv[c] = y[c] * siluf(z[c]);
    float o[16];
#pragma unroll
    for (int j = 0; j < 16; j++) {
        float acc = 0.f;
#pragma unroll
        for (int c = 0; c < 32; c++) acc += yv[c] * s_w[j * 32 + c];
        o[j] = acc * (1.0f / 3.0f);
    }
    int b = n >> 6, cube = n & 63;
    if (MODE == 0) {
        int i2 = l >> 5, j2 = l & 31;
        int io = i2 >> 1, jo = j2 >> 1;
        int coff = ((i2 & 1) << 1) | (j2 & 1);
#pragma unroll
        for (int j = 0; j < 16; j++) out[oidx(b, cube, j * 4 + coff, io, jo)] = o[j];
    } else if (MODE == 1) {
        int c = l >> 4, jj = l & 15;
#pragma unroll
        for (int j = 0; j < 16; j++) out[oidx(b, cube, c, j, jj)] += o[j];
    } else {
        int c = l >> 4, ii = l & 15;
#pragma unroll
        for (int j = 0; j < 16; j++) out[oidx(b, cube, c, ii, j)] += o[j];
    }
}

}  // namespace

extern "C" void kernel_launch(void* const* d_in, const int* in_sizes, int n_in,
                              void* d_out, int out_size, void* d_ws, size_t ws_size,
                              hipStream_t stream) {
    const float* x   = (const float*)d_in[0];
    const float* gt1 = (const float*)d_in[1];
    const float* gt2 = (const float*)d_in[2];
    const float* ln1g = (const float*)d_in[3];
    const float* ln1b = (const float*)d_in[4];
    const float* ln2g = (const float*)d_in[5];
    const float* ln2b = (const float*)d_in[6];
    const float* m[2][9];
    for (int mi = 0; mi < 2; mi++)
        for (int k = 0; k < 9; k++) m[mi][k] = (const float*)d_in[7 + mi * 9 + k];
    float* out = (float*)d_out;

    float* ws = (float*)d_ws;
    float* XZ = ws;                               // 128*1025*64 f32 (33.6 MB)
    float* SC = XZ + (size_t)NSEQ * TLEN * 64;    // 128*1025*96 f32 (50.4 MB)
    float* YC = SC + (size_t)NSEQ * TLEN * 96;    // 128*1025*32 f32 (16.8 MB)

    const int ntok = NSEQ * TLEN;
    dim3 blk(256), grd((ntok + 255) / 256);
    const int ntok3 = NSEQ * LSEQ;
    dim3 grd3((ntok3 + 255) / 256);

    for (int mode = 0; mode < 3; mode++) {
        int pi = (mode == 0) ? 0 : 1;
        const float* gt = (mode == 0) ? gt1 : gt2;
        const float* lg = (mode == 0) ? ln1g : ln2g;
        const float* lb = (mode == 0) ? ln1b : ln2b;
        const float* const* P = m[pi];
        // P: 0 in_w, 1 conv_w, 2 conv_b, 3 xproj_w, 4 dt_w, 5 dt_b, 6 A_log, 7 D, 8 out_w
        if (mode == 0)      k_p1a<0><<<grd, blk, 0, stream>>>(x, gt, lg, lb, P[0], XZ);
        else if (mode == 1) k_p1a<1><<<grd, blk, 0, stream>>>(x, gt, lg, lb, P[0], XZ);
        else                k_p1a<2><<<grd, blk, 0, stream>>>(x, gt, lg, lb, P[0], XZ);
        k_p1b<<<grd, blk, 0, stream>>>(XZ, P[1], P[2], P[3], P[4], P[5], SC);
        k_scan<<<dim3(NSEQ), dim3(512), 0, stream>>>(SC, P[6], P[7], YC);
        if (mode == 0)      k_p3<0><<<grd3, blk, 0, stream>>>(YC, XZ, P[8], out);
        else if (mode == 1) k_p3<1><<<grd3, blk, 0, stream>>>(YC, XZ, P[8], out);
        else                k_p3<2><<<grd3, blk, 0, stream>>>(YC, XZ, P[8], out);
    }
}

// Round 2
// 666.514 us; speedup vs baseline: 1.7374x; 1.7374x over previous
//
#include <hip/hip_runtime.h>
#include <cmath>

namespace {

constexpr int XC = 64, XH = 128, XW = 128;
constexpr int NSEQ = 128;   // B(2) * 64 cubes
constexpr int TLEN = 1025;  // gt token + 1024
constexpr int LSEQ = 1024;
constexpr int NCH = 16;     // chunks per sequence for the parallel scan
constexpr int CHUNK = 65;   // ceil(1025/16); 16*65 = 1040 >= 1025

__device__ __forceinline__ int xidx(int b, int c, int h, int w) {
    return ((b * XC + c) * XH + h) * XW + w;
}
// reference's final reassembly: linear=(cube*256+i*16+j) -> h=lin>>7, w=lin&127
__device__ __forceinline__ int oidx(int b, int cube, int c, int i, int j) {
    int h = cube * 2 + (i >> 3);
    int w = ((i & 7) << 4) | j;
    return xidx(b, c, h, w);
}
__device__ __forceinline__ float siluf(float v) { return v / (1.0f + __expf(-v)); }
__device__ __forceinline__ float softplusf(float v) {
    return v > 20.0f ? v : log1pf(__expf(v));
}

// ---------------- phase 1a: gather + layernorm + in-proj (16 -> 64) ----------
template <int MODE>
__global__ void k_p1a(const float* __restrict__ x, const float* __restrict__ gt,
                      const float* __restrict__ lng, const float* __restrict__ lnb,
                      const float* __restrict__ in_w,  // (64,16)
                      float* __restrict__ xz)          // (NSEQ,TLEN,64): [0:32]=xi [32:64]=z
{
    __shared__ float s_w[64 * 16];
    __shared__ float s_g[16], s_b[16], s_gt[16];
    for (int i = threadIdx.x; i < 64 * 16; i += blockDim.x) s_w[i] = in_w[i];
    if (threadIdx.x < 16) {
        s_g[threadIdx.x] = lng[threadIdx.x];
        s_b[threadIdx.x] = lnb[threadIdx.x];
        s_gt[threadIdx.x] = gt[threadIdx.x];
    }
    __syncthreads();
    int tid = blockIdx.x * blockDim.x + threadIdx.x;
    if (tid >= NSEQ * TLEN) return;
    int n = tid / TLEN, t = tid - n * TLEN;

    float v[16];
    if (t == 0) {
#pragma unroll
        for (int i = 0; i < 16; i++) v[i] = s_gt[i];
    } else {
        int l = t - 1;
        int b = n >> 6, cube = n & 63, bi = cube >> 3, bj = cube & 7;
        if (MODE == 0) {
            int i2 = l >> 5, j2 = l & 31;
            int h = bi * 16 + (i2 >> 1), w = bj * 16 + (j2 >> 1);
            int coff = ((i2 & 1) << 1) | (j2 & 1);
#pragma unroll
            for (int i = 0; i < 16; i++) v[i] = x[xidx(b, i * 4 + coff, h, w)];
        } else if (MODE == 1) {
            int c = l >> 4, j = l & 15;
            int w = bj * 16 + j;
#pragma unroll
            for (int i = 0; i < 16; i++) v[i] = x[xidx(b, c, bi * 16 + i, w)];
        } else {
            int c = l >> 4, i = l & 15;
            int h = bi * 16 + i;
#pragma unroll
            for (int j = 0; j < 16; j++) v[j] = x[xidx(b, c, h, bj * 16 + j)];
        }
    }
    // layernorm over 16
    float mu = 0.f;
#pragma unroll
    for (int i = 0; i < 16; i++) mu += v[i];
    mu *= (1.0f / 16.0f);
    float var = 0.f;
#pragma unroll
    for (int i = 0; i < 16; i++) { float d = v[i] - mu; var += d * d; }
    var *= (1.0f / 16.0f);
    float inv = rsqrtf(var + 1e-5f);
#pragma unroll
    for (int i = 0; i < 16; i++) v[i] = (v[i] - mu) * inv * s_g[i] + s_b[i];
    // in-proj
    float* o = xz + (size_t)tid * 64;
#pragma unroll
    for (int oc = 0; oc < 64; oc++) {
        float acc = 0.f;
#pragma unroll
        for (int i = 0; i < 16; i++) acc += v[i] * s_w[oc * 16 + i];
        o[oc] = acc;
    }
}

// ------------- phase 1b: causal conv4 + silu + x-proj + dt/softplus ----------
__global__ void k_p1b(const float* __restrict__ xz,
                      const float* __restrict__ conv_w,  // (32,4)
                      const float* __restrict__ conv_b,  // (32)
                      const float* __restrict__ xproj_w, // (33,32)
                      const float* __restrict__ dt_w,    // (32,1)
                      const float* __restrict__ dt_b,    // (32)
                      float* __restrict__ sc)            // (NSEQ,TLEN,96): xc[32] dt[32] B[16] C[16]
{
    __shared__ float s_xp[33 * 32];
    __shared__ float s_cw[32 * 4], s_cb[32], s_dw[32], s_db[32];
    for (int i = threadIdx.x; i < 33 * 32; i += blockDim.x) s_xp[i] = xproj_w[i];
    for (int i = threadIdx.x; i < 128; i += blockDim.x) s_cw[i] = conv_w[i];
    if (threadIdx.x < 32) {
        s_cb[threadIdx.x] = conv_b[threadIdx.x];
        s_dw[threadIdx.x] = dt_w[threadIdx.x];
        s_db[threadIdx.x] = dt_b[threadIdx.x];
    }
    __syncthreads();
    int tid = blockIdx.x * blockDim.x + threadIdx.x;
    if (tid >= NSEQ * TLEN) return;
    int n = tid / TLEN, t = tid - n * TLEN;
    const float* xzn = xz + (size_t)n * TLEN * 64;

    float xc[32];
#pragma unroll
    for (int c = 0; c < 32; c++) xc[c] = 0.f;
#pragma unroll
    for (int k = 0; k < 4; k++) {
        int tk = t - 3 + k;
        if (tk >= 0) {
            const float* row = xzn + (size_t)tk * 64;
#pragma unroll
            for (int c = 0; c < 32; c++) xc[c] += s_cw[c * 4 + k] * row[c];
        }
    }
#pragma unroll
    for (int c = 0; c < 32; c++) xc[c] = siluf(xc[c] + s_cb[c]);

    float dt0 = 0.f;
#pragma unroll
    for (int c = 0; c < 32; c++) dt0 += xc[c] * s_xp[c];  // x_dbl row 0 (dt_rank=1)

    float* out = sc + (size_t)tid * 96;
#pragma unroll
    for (int c = 0; c < 32; c++) out[c] = xc[c];
#pragma unroll
    for (int d = 0; d < 32; d++) out[32 + d] = softplusf(dt0 * s_dw[d] + s_db[d]);
#pragma unroll
    for (int r = 0; r < 32; r++) {  // rows 1..32 -> B[0:16], C[0:16]
        float acc = 0.f;
#pragma unroll
        for (int c = 0; c < 32; c++) acc += xc[c] * s_xp[(1 + r) * 32 + c];
        out[64 + r] = acc;
    }
}

// -------- phase 2a: per-chunk scan summaries (P = prod a, F = h from 0) -----
__global__ __launch_bounds__(512) void k_scan1(const float* __restrict__ sc,
                                               const float* __restrict__ A_log,
                                               float* __restrict__ Psum,
                                               float* __restrict__ Fsum)
{
    int n = blockIdx.x >> 4;        // / NCH
    int c = blockIdx.x & (NCH - 1);
    int t0 = c * CHUNK;
    int nt = min(CHUNK, TLEN - t0);
    __shared__ float s_sc[CHUNK * 96];
    const float* src = sc + ((size_t)n * TLEN + t0) * 96;
    int nv4 = (nt * 96) >> 2;       // nt*96 divisible by 4
    for (int i = threadIdx.x; i < nv4; i += 512)
        ((float4*)s_sc)[i] = ((const float4*)src)[i];
    int tid = threadIdx.x, d = tid >> 4, s = tid & 15;
    float A = -__expf(A_log[tid]);  // A_log[d*16+s] == A_log[tid]
    __syncthreads();
    float h = 0.f, P = 1.f;
    for (int t = 0; t < nt; t++) {
        const float* p = s_sc + t * 96;
        float dt = p[32 + d], xc = p[d], Bv = p[64 + s];
        float a = __expf(dt * A);
        h = a * h + dt * Bv * xc;
        P *= a;
    }
    size_t idx = ((size_t)n * NCH + c) * 512 + tid;
    Psum[idx] = P;
    Fsum[idx] = h;
}

// -------- phase 2b: combine chunk summaries -> incoming state per chunk -----
__global__ __launch_bounds__(512) void k_comb(const float* __restrict__ Psum,
                                              const float* __restrict__ Fsum,
                                              float* __restrict__ Hin)
{
    int n = blockIdx.x, tid = threadIdx.x;
    const float* pb = Psum + (size_t)n * NCH * 512;
    const float* fb = Fsum + (size_t)n * NCH * 512;
    float P[NCH], F[NCH];
#pragma unroll
    for (int c = 0; c < NCH; c++) {
        P[c] = pb[(size_t)c * 512 + tid];
        F[c] = fb[(size_t)c * 512 + tid];
    }
    float* hb = Hin + (size_t)n * NCH * 512;
    float H = 0.f;
#pragma unroll
    for (int c = 0; c < NCH; c++) {
        hb[(size_t)c * 512 + tid] = H;
        H = F[c] + P[c] * H;
    }
}

// -------- phase 2c: per-chunk scan with true incoming state, emit y ---------
__global__ __launch_bounds__(512) void k_scan2(const float* __restrict__ sc,
                                               const float* __restrict__ A_log,
                                               const float* __restrict__ Dp,
                                               const float* __restrict__ Hin,
                                               float* __restrict__ yc)  // (NSEQ,TLEN,32)
{
    int n = blockIdx.x >> 4;
    int c = blockIdx.x & (NCH - 1);
    int t0 = c * CHUNK;
    int nt = min(CHUNK, TLEN - t0);
    __shared__ float s_sc[CHUNK * 96];
    __shared__ float s_y[CHUNK * 32];
    const float* src = sc + ((size_t)n * TLEN + t0) * 96;
    int nv4 = (nt * 96) >> 2;
    for (int i = threadIdx.x; i < nv4; i += 512)
        ((float4*)s_sc)[i] = ((const float4*)src)[i];
    int tid = threadIdx.x, d = tid >> 4, s = tid & 15;
    float A = -__expf(A_log[tid]);
    float Dd = Dp[d];
    float h = Hin[((size_t)n * NCH + c) * 512 + tid];
    __syncthreads();
    for (int t = 0; t < nt; t++) {
        const float* p = s_sc + t * 96;
        float dt = p[32 + d], xc = p[d], Bv = p[64 + s], Cv = p[80 + s];
        float a = __expf(dt * A);
        h = a * h + dt * Bv * xc;
        float pp = h * Cv;
        pp += __shfl_xor(pp, 1);
        pp += __shfl_xor(pp, 2);
        pp += __shfl_xor(pp, 4);
        pp += __shfl_xor(pp, 8);
        if (s == 0) s_y[t * 32 + d] = pp + Dd * xc;
    }
    __syncthreads();
    float* yb = yc + ((size_t)n * TLEN + t0) * 32;
    int ny4 = (nt * 32) >> 2;
    for (int i = threadIdx.x; i < ny4; i += 512)
        ((float4*)yb)[i] = ((const float4*)s_y)[i];
}

// ---------------- phase 3: gate + out-proj + scatter ------------------------
template <int MODE>
__global__ void k_p3(const float* __restrict__ yc, const float* __restrict__ xz,
                     const float* __restrict__ out_w,  // (16,32)
                     float* __restrict__ out)
{
    __shared__ float s_w[16 * 32];
    for (int i = threadIdx.x; i < 512; i += blockDim.x) s_w[i] = out_w[i];
    __syncthreads();
    int tid = blockIdx.x * blockDim.x + threadIdx.x;
    if (tid >= NSEQ * LSEQ) return;
    int n = tid >> 10, l = tid & 1023, t = l + 1;
    const float* y = yc + ((size_t)n * TLEN + t) * 32;
    const float* z = xz + ((size_t)n * TLEN + t) * 64 + 32;
    float yv[32];
#pragma unroll
    for (int c = 0; c < 32; c++) yv[c] = y[c] * siluf(z[c]);
    float o[16];
#pragma unroll
    for (int j = 0; j < 16; j++) {
        float acc = 0.f;
#pragma unroll
        for (int c = 0; c < 32; c++) acc += yv[c] * s_w[j * 32 + c];
        o[j] = acc * (1.0f / 3.0f);
    }
    int b = n >> 6, cube = n & 63;
    if (MODE == 0) {
        int i2 = l >> 5, j2 = l & 31;
        int io = i2 >> 1, jo = j2 >> 1;
        int coff = ((i2 & 1) << 1) | (j2 & 1);
#pragma unroll
        for (int j = 0; j < 16; j++) out[oidx(b, cube, j * 4 + coff, io, jo)] = o[j];
    } else if (MODE == 1) {
        int c = l >> 4, jj = l & 15;
#pragma unroll
        for (int j = 0; j < 16; j++) out[oidx(b, cube, c, j, jj)] += o[j];
    } else {
        int c = l >> 4, ii = l & 15;
#pragma unroll
        for (int j = 0; j < 16; j++) out[oidx(b, cube, c, ii, j)] += o[j];
    }
}

}  // namespace

extern "C" void kernel_launch(void* const* d_in, const int* in_sizes, int n_in,
                              void* d_out, int out_size, void* d_ws, size_t ws_size,
                              hipStream_t stream) {
    const float* x   = (const float*)d_in[0];
    const float* gt1 = (const float*)d_in[1];
    const float* gt2 = (const float*)d_in[2];
    const float* ln1g = (const float*)d_in[3];
    const float* ln1b = (const float*)d_in[4];
    const float* ln2g = (const float*)d_in[5];
    const float* ln2b = (const float*)d_in[6];
    const float* m[2][9];
    for (int mi = 0; mi < 2; mi++)
        for (int k = 0; k < 9; k++) m[mi][k] = (const float*)d_in[7 + mi * 9 + k];
    float* out = (float*)d_out;

    float* ws = (float*)d_ws;
    float* XZ = ws;                               // 128*1025*64 f32 (33.6 MB)
    float* SC = XZ + (size_t)NSEQ * TLEN * 64;    // 128*1025*96 f32 (50.4 MB)
    float* YC = SC + (size_t)NSEQ * TLEN * 96;    // 128*1025*32 f32 (16.8 MB)
    float* PS = YC + (size_t)NSEQ * TLEN * 32;    // 128*16*512 f32 (4.2 MB)
    float* FS = PS + (size_t)NSEQ * NCH * 512;    // 4.2 MB
    float* HI = FS + (size_t)NSEQ * NCH * 512;    // 4.2 MB

    const int ntok = NSEQ * TLEN;
    dim3 blk(256), grd((ntok + 255) / 256);
    const int ntok3 = NSEQ * LSEQ;
    dim3 grd3((ntok3 + 255) / 256);
    dim3 gscan(NSEQ * NCH);

    for (int mode = 0; mode < 3; mode++) {
        int pi = (mode == 0) ? 0 : 1;
        const float* gt = (mode == 0) ? gt1 : gt2;
        const float* lg = (mode == 0) ? ln1g : ln2g;
        const float* lb = (mode == 0) ? ln1b : ln2b;
        const float* const* P = m[pi];
        // P: 0 in_w, 1 conv_w, 2 conv_b, 3 xproj_w, 4 dt_w, 5 dt_b, 6 A_log, 7 D, 8 out_w
        if (mode == 0)      k_p1a<0><<<grd, blk, 0, stream>>>(x, gt, lg, lb, P[0], XZ);
        else if (mode == 1) k_p1a<1><<<grd, blk, 0, stream>>>(x, gt, lg, lb, P[0], XZ);
        else                k_p1a<2><<<grd, blk, 0, stream>>>(x, gt, lg, lb, P[0], XZ);
        k_p1b<<<grd, blk, 0, stream>>>(XZ, P[1], P[2], P[3], P[4], P[5], SC);
        k_scan1<<<gscan, dim3(512), 0, stream>>>(SC, P[6], PS, FS);
        k_comb<<<dim3(NSEQ), dim3(512), 0, stream>>>(PS, FS, HI);
        k_scan2<<<gscan, dim3(512), 0, stream>>>(SC, P[6], P[7], HI, YC);
        if (mode == 0)      k_p3<0><<<grd3, blk, 0, stream>>>(YC, XZ, P[8], out);
        else if (mode == 1) k_p3<1><<<grd3, blk, 0, stream>>>(YC, XZ, P[8], out);
        else                k_p3<2><<<grd3, blk, 0, stream>>>(YC, XZ, P[8], out);
    }
}